// Round 6
// baseline (1912.425 us; speedup 1.0000x reference)
//
#include <hip/hip_runtime.h>
#include <math.h>

// ---------------- problem constants (fixed inputs: key 0) ----------------
#define BN 16384
#define DN 1024
#define CHEB_D 10  // Chebyshev degree per stage IN M (== degree 20 in C)

// ---------------- workspace layout (bytes, all 256-aligned) ----------------
static constexpr size_t OFF_C    = 0x000000;  // f32 [1024*1024]  G -> C -> Chat   [ZERO]
static constexpr size_t OFF_P    = 0x400000;  // f32 [16][64][1024] mv partials
static constexpr size_t OFF_Y0   = 0x800000;  // f32 [64][1024]
static constexpr size_t OFF_Y1   = 0x840000;
static constexpr size_t OFF_Y2   = 0x880000;
static constexpr size_t OFF_Y3   = 0x8C0000;
static constexpr size_t OFF_CQ   = 0x900000;  // f32 [64][1024]
static constexpr size_t OFF_S64  = 0x940000;  // f64 [64*64] gram
static constexpr size_t OFF_LF   = 0x948000;  // f32 [64*64] chol factor (recip diag)
static constexpr size_t OFF_T64  = 0x950000;  // f64 [64*64] RR matrix (in M-space)
static constexpr size_t OFF_V16  = 0x958000;  // f32 [64*16] top-16 eigvecs
static constexpr size_t OFF_UT   = 0x960000;  // f32 [16][1024]
static constexpr size_t OFF_UTT  = 0x970000;  // f32 [1024][16]
static constexpr size_t OFF_S16  = 0x980000;  // f32 [16]
static constexpr size_t OFF_CS   = 0x980100;  // f32 [1024] colsum           [ZERO]
static constexpr size_t OFF_TR   = 0x981100;  // f32 [1] trace               [ZERO]
static constexpr size_t OFF_SCAL = 0x981200;  // f32 [2] mid, inv_e
static constexpr size_t OFF_STAT = 0x981300;  // f32 [10*153] stats          [ZERO]
static constexpr size_t OFF_F    = 0x990000;  // f32 [16384*16] features
static constexpr size_t OFF_M    = 0xA90000;  // f32 [1024*1024] M = 2*Chat^2 - I [ZERO]
// end 0xE90000 (~15.6 MB of ws used)

// ---------------- kernels ----------------

__global__ __launch_bounds__(256) void colsum_k(const float* __restrict__ X, float* __restrict__ cs){
  int b = blockIdx.x, t = threadIdx.x;
  float a0=0.f,a1=0.f,a2=0.f,a3=0.f;
  for (int r=0; r<256; ++r){
    const float4 v = *(const float4*)(X + (size_t)(b*256 + r)*1024 + t*4);
    a0 += v.x; a1 += v.y; a2 += v.z; a3 += v.w;
  }
  atomicAdd(&cs[t*4+0], a0); atomicAdd(&cs[t*4+1], a1);
  atomicAdd(&cs[t*4+2], a2); atomicAdd(&cs[t*4+3], a3);
}

// SYRK body: upper 128x128 tiles of A^T A, conflict-free fragment layout.
template<int KCHUNK>
__device__ __forceinline__ void syrk_body(const float* __restrict__ X, float* __restrict__ G, int KMAX){
  int bx = blockIdx.x;
  int tp = bx % 36, ks = bx / 36;
  int ti = 0, rem = tp;
  while (rem >= 8 - ti){ rem -= 8 - ti; ++ti; }
  int tj = ti + rem;                      // ti <= tj
  int k0 = ks * KCHUNK;
  int kend = k0 + KCHUNK; if (kend > KMAX) kend = KMAX;
  __shared__ __attribute__((aligned(16))) float Xa[16][132];
  __shared__ __attribute__((aligned(16))) float Xb[16][132];
  int t = threadIdx.x;
  int tx = t & 15, ty = t >> 4;
  int kk0 = t >> 5, f4 = t & 31;
  const float* ba = X + (size_t)kk0*1024 + ti*128 + f4*4;
  const float* bb = X + (size_t)kk0*1024 + tj*128 + f4*4;
  float4 pa0, pa1, pb0, pb1;
  {
    size_t o = (size_t)k0*1024;
    pa0 = *(const float4*)(ba + o);
    pb0 = *(const float4*)(bb + o);
    pa1 = *(const float4*)(ba + o + 8*1024);
    pb1 = *(const float4*)(bb + o + 8*1024);
  }
  float acc[8][8];
  #pragma unroll
  for (int i=0;i<8;++i)
    #pragma unroll
    for (int j=0;j<8;++j) acc[i][j] = 0.f;
  for (int kc = k0; kc < kend; kc += 16){
    __syncthreads();
    *(float4*)&Xa[kk0][f4*4]   = pa0;
    *(float4*)&Xa[kk0+8][f4*4] = pa1;
    *(float4*)&Xb[kk0][f4*4]   = pb0;
    *(float4*)&Xb[kk0+8][f4*4] = pb1;
    __syncthreads();
    if (kc + 16 < kend){
      size_t o = (size_t)(kc+16)*1024;
      pa0 = *(const float4*)(ba + o);
      pb0 = *(const float4*)(bb + o);
      pa1 = *(const float4*)(ba + o + 8*1024);
      pb1 = *(const float4*)(bb + o + 8*1024);
    }
    #pragma unroll
    for (int kk=0; kk<16; ++kk){
      float a[8], b[8];
      *(float4*)&a[0] = *(const float4*)&Xa[kk][tx*4];
      *(float4*)&a[4] = *(const float4*)&Xa[kk][64 + tx*4];
      *(float4*)&b[0] = *(const float4*)&Xb[kk][ty*4];
      *(float4*)&b[4] = *(const float4*)&Xb[kk][64 + ty*4];
      #pragma unroll
      for (int i=0;i<8;++i)
        #pragma unroll
        for (int j=0;j<8;++j) acc[i][j] += a[i]*b[j];
    }
  }
  #pragma unroll
  for (int i=0;i<8;++i){
    int ri = ti*128 + ((i<4) ? (tx*4+i) : (64 + tx*4 + (i-4)));
    #pragma unroll
    for (int j=0;j<8;++j){
      int cj = tj*128 + ((j<4) ? (ty*4+j) : (64 + ty*4 + (j-4)));
      atomicAdd(&G[(size_t)ri*1024 + cj], acc[i][j]);
    }
  }
}

__global__ __launch_bounds__(256, 3) void syrk_k(const float* __restrict__ X, float* __restrict__ G){
  syrk_body<688>(X, G, 16384);
}
__global__ __launch_bounds__(256, 3) void syrkM_k(const float* __restrict__ X, float* __restrict__ G){
  syrk_body<128>(X, G, 1024);
}

__global__ __launch_bounds__(256) void formC_k(float* __restrict__ C, const float* __restrict__ cs, float* __restrict__ tr){
  int g = blockIdx.x*256 + threadIdx.x;
  int i = g >> 10, j = g & 1023;
  if (j < i) return;
  float v = C[g] - cs[i]*cs[j]*(1.0f/16384.0f);
  C[g] = v;
  C[j*1024 + i] = v;
  if (i == j) atomicAdd(tr, v);
}

__global__ void scal_k(const float* __restrict__ tr, float* __restrict__ scal){
  float trD = tr[0] * (1.0f/1024.0f);
  float c = 1.40f * trD, a = 0.25f * trD;
  scal[0] = 0.5f*(c + a);       // mid
  scal[1] = 2.0f/(c - a);       // 1/e
}

__global__ __launch_bounds__(256) void formChat_k(float* __restrict__ C, const float* __restrict__ scal){
  int g = blockIdx.x*256 + threadIdx.x;
  int i = g >> 10, j = g & 1023;
  float mid = scal[0], ie = scal[1];
  C[g] = ie*(C[g] - ((i==j) ? mid : 0.f));
}

__global__ __launch_bounds__(256) void formM_k(float* __restrict__ M){
  int g = blockIdx.x*256 + threadIdx.x;
  int i = g >> 10, j = g & 1023;
  if (j < i) return;
  float v = 2.f*M[g] - ((i==j) ? 1.f : 0.f);
  M[g] = v;
  M[j*1024 + i] = v;
}

__global__ void rng_k(float* __restrict__ Y){
  int idx = blockIdx.x*256 + threadIdx.x;   // 65536
  unsigned h = (unsigned)idx * 2654435761u;
  h ^= h >> 16; h *= 2246822519u; h ^= h >> 13; h *= 3266489917u; h ^= h >> 16;
  Y[idx] = (float)(h & 0xFFFFFFu) * (2.0f/16777216.0f) - 1.0f;
}

__global__ __launch_bounds__(256) void mv_k(const float* __restrict__ Yt, const float* __restrict__ Cm, float* __restrict__ P){
  int bx = blockIdx.x;
  int nt = bx & 15, ks = bx >> 4;
  int n0 = nt*64, k0 = ks*64;
  __shared__ __attribute__((aligned(16))) float At[64][68];
  __shared__ __attribute__((aligned(16))) float Bt[64][68];
  int t = threadIdx.x;
  #pragma unroll
  for (int w=0; w<4; ++w){
    int job = t + 256*w;
    int m  = job >> 4, f4 = job & 15;
    float4 v = *(const float4*)(Yt + (size_t)m*1024 + k0 + f4*4);
    At[f4*4+0][m] = v.x; At[f4*4+1][m] = v.y; At[f4*4+2][m] = v.z; At[f4*4+3][m] = v.w;
    int kk = job >> 4, fn = job & 15;
    *(float4*)&Bt[kk][fn*4] = *(const float4*)(Cm + (size_t)(k0+kk)*1024 + n0 + fn*4);
  }
  __syncthreads();
  int tm = t & 15, tn = t >> 4;
  float acc[4][4];
  #pragma unroll
  for (int i=0;i<4;++i)
    #pragma unroll
    for (int j=0;j<4;++j) acc[i][j]=0.f;
  for (int kk=0; kk<64; ++kk){
    float4 a = *(const float4*)&At[kk][tm*4];
    float4 b = *(const float4*)&Bt[kk][tn*4];
    float av[4] = {a.x,a.y,a.z,a.w};
    float bv[4] = {b.x,b.y,b.z,b.w};
    #pragma unroll
    for (int i=0;i<4;++i)
      #pragma unroll
      for (int j=0;j<4;++j) acc[i][j] += av[i]*bv[j];
  }
  #pragma unroll
  for (int i=0;i<4;++i){
    float4 o; o.x=acc[i][0]; o.y=acc[i][1]; o.z=acc[i][2]; o.w=acc[i][3];
    *(float4*)(P + (size_t)(ks*64 + tm*4 + i)*1024 + n0 + tn*4) = o;
  }
}

__global__ __launch_bounds__(256) void combine_k(const float* __restrict__ P, const float* __restrict__ Tk1,
                                                 float* __restrict__ out, int mode){
  int idx = (blockIdx.x*256 + threadIdx.x)*4;
  float s0=0.f,s1=0.f,s2=0.f,s3=0.f;
  #pragma unroll
  for (int ks=0; ks<16; ++ks){
    const float4 p = *(const float4*)(P + (size_t)ks*65536 + idx);
    s0 += p.x; s1 += p.y; s2 += p.z; s3 += p.w;
  }
  float4 o;
  if (mode == 0){
    o.x=s0; o.y=s1; o.z=s2; o.w=s3;
  } else {
    const float4 t1 = *(const float4*)(Tk1 + idx);
    o.x = 2.f*s0 - t1.x; o.y = 2.f*s1 - t1.y;
    o.z = 2.f*s2 - t1.z; o.w = 2.f*s3 - t1.w;
  }
  *(float4*)(out+idx) = o;
}

__global__ __launch_bounds__(256) void gram_k(const float* __restrict__ A, const float* __restrict__ Bm, double* __restrict__ S){
  int bx = blockIdx.x;
  int i = bx >> 2, jg = bx & 3;
  __shared__ __attribute__((aligned(16))) float Ai[1024];
  __shared__ double red[16][17];
  int t = threadIdx.x;
  ((float4*)Ai)[t] = ((const float4*)(A + (size_t)i*1024))[t];
  __syncthreads();
  int jl = t >> 4, kp = t & 15;
  const float* Br = Bm + (size_t)(jg*16 + jl)*1024 + kp*64;
  const float* Ar = Ai + kp*64;
  double acc = 0.0;
  #pragma unroll 8
  for (int kk=0; kk<64; ++kk) acc += (double)Br[kk] * (double)Ar[kk];
  red[jl][kp] = acc;
  __syncthreads();
  if (t < 16){
    double s = 0.0;
    #pragma unroll
    for (int p2=0; p2<16; ++p2) s += red[t][p2];
    S[i*64 + jg*16 + t] = s;
  }
}

// fp64 Cholesky of 64x64, single wave, fixed-trip masked rank-1 updates.
__global__ __launch_bounds__(64) void chol_k(const double* __restrict__ S, float* __restrict__ Lf){
  __shared__ double L[64][65];
  __shared__ double col[64];
  int t = threadIdx.x;
  for (int e=t; e<4096; e+=64) L[e>>6][e&63] = S[e];
  __syncthreads();
  for (int k=0; k<64; ++k){
    double lkk = sqrt(fmax(L[k][k], 1e-280));
    double r = 1.0/lkk;
    double ck = (t > k) ? L[t][k]*r : 0.0;
    col[t] = ck;
    if (t == k) L[k][k] = lkk;
    if (t > k)  L[t][k] = ck;
    __syncthreads();
    #pragma unroll
    for (int j=0; j<64; j+=8){
      L[t][j+0] -= ck*col[j+0];
      L[t][j+1] -= ck*col[j+1];
      L[t][j+2] -= ck*col[j+2];
      L[t][j+3] -= ck*col[j+3];
      L[t][j+4] -= ck*col[j+4];
      L[t][j+5] -= ck*col[j+5];
      L[t][j+6] -= ck*col[j+6];
      L[t][j+7] -= ck*col[j+7];
    }
    __syncthreads();
  }
  for (int e=t; e<4096; e+=64){
    int i = e >> 6, j = e & 63;
    Lf[e] = (j < i) ? (float)L[i][j] : ((j == i) ? (float)(1.0/L[i][i]) : 0.f);
  }
}

__global__ __launch_bounds__(256) void applysolve_k(const float* __restrict__ Yin, const float* __restrict__ Lf, float* __restrict__ Qout){
  int k = blockIdx.x*256 + threadIdx.x;
  float z[64];
  #pragma unroll
  for (int c=0; c<64; ++c){
    float v = Yin[(size_t)c*1024 + k];
    #pragma unroll
    for (int j=0; j<c; ++j) v -= Lf[c*64+j]*z[j];
    z[c] = v * Lf[c*64+c];   // diag stores reciprocal
  }
  #pragma unroll
  for (int c=0; c<64; ++c) Qout[(size_t)c*1024 + k] = z[c];
}

// ---------- single-wave 64x64 symmetric top-16 eigensolver (register-resident) ----------
__device__ __forceinline__ double wsumd(double v){
  #pragma unroll
  for (int off=32; off; off>>=1) v += __shfl_xor(v, off, 64);
  return v;
}
__device__ __forceinline__ float wsumf(float v){
  #pragma unroll
  for (int off=32; off; off>>=1) v += __shfl_xor(v, off, 64);
  return v;
}
__device__ __forceinline__ double wmind(double v){
  #pragma unroll
  for (int off=32; off; off>>=1) v = fmin(v, __shfl_xor(v, off, 64));
  return v;
}
__device__ __forceinline__ double wmaxd(double v){
  #pragma unroll
  for (int off=32; off; off>>=1) v = fmax(v, __shfl_xor(v, off, 64));
  return v;
}

__global__ __launch_bounds__(64) void eig16_k(const double* __restrict__ Tin, float* __restrict__ V16){
  __shared__ double vbufS[64], qbufS[64];
  __shared__ double eeS[64], kapS[64], ddS[64];
  __shared__ float vrefl[62][64];     // reflectors (fp32, for back-transform)
  __shared__ float dF[64], eF[64], e2F[64];
  __shared__ float lamF[16];
  __shared__ float W[16][68];
  int t = threadIdx.x;               // single wave of 64

  // ---- load row t into registers, symmetrized (both reads L2-hot) ----
  double ar[64];
  #pragma unroll
  for (int j=0; j<64; ++j)
    ar[j] = 0.5*(Tin[t*64 + j] + Tin[(size_t)j*64 + t]);

  double colv = ar[0];               // tracked A[t][k] for current k

  // ---- Householder tridiagonalization, matrix in VGPRs ----
  for (int k=0; k<62; ++k){
    double ck = (t > k) ? colv : 0.0;
    double sigma = wsumd(ck*ck);
    double x1 = __shfl(colv, k+1, 64);           // A[k+1][k]
    double r = sqrt(sigma);
    double alpha = (x1 >= 0.0) ? -r : r;
    double kappa = sigma - alpha*x1;             // >= 0
    double kinv = (kappa > 1e-280) ? 1.0/kappa : 0.0;
    double v_own = ck;
    if (t == k+1) v_own = x1 - alpha;
    if (kinv == 0.0) v_own = 0.0;
    vrefl[k][t] = (float)v_own;
    vbufS[t] = v_own;
    if (t == 0){ eeS[k] = (kinv == 0.0) ? 0.0 : alpha; kapS[k] = (kinv == 0.0) ? 0.0 : kappa; }
    __syncthreads();
    // p = A v  (row dot from registers; vbufS broadcast reads)
    double p0=0.0,p1=0.0,p2=0.0,p3=0.0;
    #pragma unroll
    for (int j=0; j<64; j+=4){
      p0 += ar[j+0]*vbufS[j+0];
      p1 += ar[j+1]*vbufS[j+1];
      p2 += ar[j+2]*vbufS[j+2];
      p3 += ar[j+3]*vbufS[j+3];
    }
    double pi = (t > k) ? ((p0+p1)+(p2+p3))*kinv : 0.0;
    double vp = wsumd(v_own*pi);
    double Kc = vp * 0.5 * kinv;
    double q_own = (t > k) ? (pi - Kc*v_own) : 0.0;
    qbufS[t] = q_own;
    __syncthreads();
    // A -= v q^T + q v^T ; track next column k+1
    double nextcol = 0.0;
    #pragma unroll
    for (int j=0; j<64; ++j){
      double nv = ar[j] - v_own*qbufS[j] - q_own*vbufS[j];
      ar[j] = nv;
      if (j == k+1) nextcol = nv;    // k is wave-uniform: cheap select
    }
    colv = nextcol;
    __syncthreads();
  }

  // ---- extract tridiagonal ----
  double dd_own = 0.0;
  #pragma unroll
  for (int j=0; j<64; ++j){
    double dj = __shfl(ar[j], j, 64);            // A[j][j], uniform
    if (t == j) dd_own = dj;
  }
  ddS[t] = dd_own;
  if (t == 0){
    eeS[63] = 0.0;
  }
  __syncthreads();
  if (t == 0){
    // ee[62] = A[63][62] = lane63 colv after last iter — grab via ddS-style store:
  }
  // lane 63 publishes A[63][62] (its colv after k=61)
  if (t == 63) eeS[62] = colv;
  __syncthreads();
  dF[t] = (float)ddS[t];
  eF[t] = (float)eeS[t];
  e2F[t] = (float)(eeS[t]*eeS[t]);
  __syncthreads();

  // ---- Gershgorin bounds ----
  double em1 = (t > 0) ? fabs(eeS[t-1]) : 0.0;
  double ep  = fabs(eeS[t]);
  double glo = wmind(ddS[t] - em1 - ep);
  double ghi = wmaxd(ddS[t] + em1 + ep);
  double span = ghi - glo + 1.0;
  float lo = (float)(glo - 0.001*span), hi = (float)(ghi + 0.001*span);

  // ---- Sturm bisection: lane -> eigenvalue index 48 + (lane&15) ----
  int m = 48 + (t & 15);
  const float PIV = 1e-10f;
  for (int it=0; it<30; ++it){
    float x = 0.5f*(lo + hi);
    float q = dF[0] - x;
    int c = (q < 0.f) ? 1 : 0;
    #pragma unroll 1
    for (int j=1; j<64; ++j){
      float qs = (fabsf(q) < PIV) ? ((q < 0.f) ? -PIV : PIV) : q;
      q = dF[j] - x - e2F[j-1]/qs;
      c += (q < 0.f) ? 1 : 0;
    }
    if (c <= m) lo = x; else hi = x;
  }
  if (t < 16) lamF[t] = 0.5f*(lo + hi);
  __syncthreads();

  // ---- inverse iteration (lanes 0..15), register-resident tridiagonal LU ----
  if (t < 16){
    float lam = lamF[t];
    const float PIVF = 1e-6f;
    float DD[64], DL[64], DU[64], DU2[64], B[64];
    #pragma unroll
    for (int i=0; i<64; ++i){
      DD[i] = dF[i] - lam;
      DU2[i] = 0.f;
      if (i < 63){ DU[i] = eF[i]; DL[i] = eF[i]; }
      unsigned hsh = (unsigned)(i*131 + t*1009 + 7);
      hsh ^= hsh >> 13; hsh *= 2654435761u; hsh ^= hsh >> 16;
      B[i] = (float)(hsh & 0xFFFF) * (1.5f/65536.0f) + 0.25f;
    }
    unsigned long long piv = 0ull;
    #pragma unroll
    for (int i=0; i<63; ++i){
      float di = DD[i], dli = DL[i];
      if (fabsf(di) >= fabsf(dli)){
        if (fabsf(di) < PIVF) di = (di < 0.f) ? -PIVF : PIVF;
        float f = dli/di;
        DD[i] = di; DL[i] = f;
        DD[i+1] -= f*DU[i];
      } else {
        float f = di/dli;
        DD[i] = dli; DL[i] = f;
        float tmp = DU[i];
        DU[i] = DD[i+1];
        DD[i+1] = tmp - f*DD[i+1];
        if (i < 62){ DU2[i] = DU[i+1]; DU[i+1] = -f*DU[i+1]; }
        piv |= (1ull << i);
      }
    }
    #pragma unroll 1
    for (int iter=0; iter<2; ++iter){
      #pragma unroll
      for (int i=0; i<63; ++i){
        if (!((piv >> i) & 1ull)){
          B[i+1] -= DL[i]*B[i];
        } else {
          float tm = B[i];
          B[i] = B[i+1];
          B[i+1] = tm - DL[i]*B[i];
        }
      }
      float p63 = DD[63]; if (fabsf(p63) < PIVF) p63 = (p63 < 0.f) ? -PIVF : PIVF;
      B[63] = B[63]/p63;
      float p62 = DD[62]; if (fabsf(p62) < PIVF) p62 = (p62 < 0.f) ? -PIVF : PIVF;
      B[62] = (B[62] - DU[62]*B[63])/p62;
      #pragma unroll
      for (int i=61; i>=0; --i){
        float pi2 = DD[i]; if (fabsf(pi2) < PIVF) pi2 = (pi2 < 0.f) ? -PIVF : PIVF;
        B[i] = (B[i] - DU[i]*B[i+1] - DU2[i]*B[i+2])/pi2;
      }
      float ss = 0.f;
      #pragma unroll
      for (int i=0; i<64; ++i){ float z = B[i]; ss += z*z; }
      float rn = rsqrtf(fmaxf(ss, 1e-30f));
      #pragma unroll
      for (int i=0; i<64; ++i) B[i] *= rn;
    }
    #pragma unroll
    for (int i=0; i<64; ++i) W[t][i] = B[i];
  }
  __syncthreads();

  // ---- MGS re-orth (lanes = element index) ----
  for (int c=0; c<16; ++c){
    float wi = W[c][t];
    float s2 = wsumf(wi*wi);
    float rn = rsqrtf(fmaxf(s2, 1e-30f));
    wi *= rn;
    W[c][t] = wi;
    for (int c2=c+1; c2<16; ++c2){
      float d2 = wsumf(wi * W[c2][t]);
      W[c2][t] -= d2*wi;
    }
    __syncthreads();
  }

  // ---- back-transform through Householder reflectors ----
  int cc = t >> 2, part = t & 3;
  for (int k=61; k>=0; --k){
    double kpd = kapS[k];
    if (kpd == 0.0) continue;          // wave-uniform
    float invk = (float)(1.0/kpd);
    float ps = 0.f;
    #pragma unroll
    for (int mm=0; mm<16; ++mm){
      int i = part*16 + mm;
      ps += vrefl[k][i]*W[cc][i];
    }
    ps += __shfl_xor(ps, 1, 64);
    ps += __shfl_xor(ps, 2, 64);
    float sc = ps * invk;
    #pragma unroll
    for (int mm=0; mm<16; ++mm){
      int i = part*16 + mm;
      W[cc][i] -= vrefl[k][i]*sc;
    }
    __syncthreads();
  }

  for (int e=t; e<1024; e+=64){
    int j = e >> 4, c = e & 15;
    V16[e] = W[c][j];
  }
}

__global__ __launch_bounds__(256) void buildUt_k(const float* __restrict__ V16,
                                                 const float* __restrict__ Qt, float* __restrict__ Ut, float* __restrict__ UtT){
  int bx = blockIdx.x;
  int c = bx & 15, kc = bx >> 4;
  int k = kc*256 + threadIdx.x;
  float acc = 0.f;
  #pragma unroll
  for (int j=0; j<64; ++j) acc += V16[j*16 + c] * Qt[(size_t)j*1024 + k];
  Ut[(size_t)c*1024 + k] = acc;
  UtT[(size_t)k*16 + c] = acc;
}

__global__ void s16_k(const float* __restrict__ cs, const float* __restrict__ Ut, float* __restrict__ s16){
  __shared__ float red[16][17];
  int t = threadIdx.x;
  int c = t & 15, part = t >> 4;
  float acc = 0.f;
  for (int d=0; d<64; ++d) acc += cs[part*64 + d] * Ut[(size_t)c*1024 + part*64 + d];
  red[c][part] = acc;
  __syncthreads();
  if (t < 16){
    float s = 0.f;
    #pragma unroll
    for (int p2=0; p2<16; ++p2) s += red[t][p2];
    s16[t] = s * (1.0f/16384.0f);
  }
}

__global__ __launch_bounds__(256) void proj_k(const float* __restrict__ X, const float* __restrict__ UtT,
                                              const float* __restrict__ s16, float* __restrict__ F){
  int r0 = blockIdx.x * 64;
  int t = threadIdx.x;
  __shared__ __attribute__((aligned(16))) float uts[16384];   // [1024][16]
  #pragma unroll
  for (int w=0; w<16; ++w)
    ((float4*)uts)[t + 256*w] = ((const float4*)UtT)[t + 256*w];
  __syncthreads();
  int row = t & 63, kp = t >> 6;
  const float* xr = X + (size_t)(r0 + row)*1024 + kp*256;
  const float* ut = uts + kp*256*16;
  float acc[16];
  #pragma unroll
  for (int c=0;c<16;++c) acc[c] = 0.f;
  for (int dd=0; dd<256; dd+=4){
    float4 xv4 = *(const float4*)(xr + dd);
    float xv[4] = {xv4.x, xv4.y, xv4.z, xv4.w};
    #pragma unroll
    for (int u=0; u<4; ++u)
      #pragma unroll
      for (int c=0;c<16;++c) acc[c] += xv[u] * ut[(dd+u)*16 + c];
  }
  __shared__ float part[4][64][16];
  #pragma unroll
  for (int c=0;c<16;++c) part[kp][row][c] = acc[c];
  __syncthreads();
  int cq = t >> 6;
  #pragma unroll
  for (int ccx=0; ccx<4; ++ccx){
    int c = cq*4 + ccx;
    float v = part[0][row][c] + part[1][row][c] + part[2][row][c] + part[3][row][c] - s16[c];
    F[(size_t)(r0 + row)*16 + c] = v;
  }
}

__global__ __launch_bounds__(256) void stats_k(const float* __restrict__ F, const int* __restrict__ lbl, float* __restrict__ SG){
  __shared__ float st[10][154];
  int t = threadIdx.x;
  for (int e=t; e<1540; e+=256) st[e/154][e%154] = 0.f;
  __syncthreads();
  int r = blockIdx.x*256 + t;
  float f[16];
  #pragma unroll
  for (int w=0; w<4; ++w){
    float4 v = *(const float4*)(F + (size_t)r*16 + w*4);
    f[w*4+0]=v.x; f[w*4+1]=v.y; f[w*4+2]=v.z; f[w*4+3]=v.w;
  }
  int c = lbl[r];
  if ((unsigned)c < 10u){
    float* bs = &st[c][0];
    atomicAdd(&bs[0], 1.f);
    #pragma unroll
    for (int a=0;a<16;++a) atomicAdd(&bs[1+a], f[a]);
    int sidx = 17;
    #pragma unroll
    for (int a=0;a<16;++a)
      #pragma unroll
      for (int b2=a;b2<16;++b2) atomicAdd(&bs[sidx++], f[a]*f[b2]);
  }
  __syncthreads();
  for (int e=t; e<1530; e+=256) atomicAdd(&SG[e], st[e/153][e%153]);
}

__global__ __launch_bounds__(256) void final_k(const float* __restrict__ SG, float* __restrict__ out){
  __shared__ double cnt[10], safe[10], ldet[10];
  __shared__ double mean[10][16];
  __shared__ double Sig[10][16][16];
  __shared__ double Inv[10][16][16];
  __shared__ double red[128];
  int t = threadIdx.x;
  if (t < 10){
    double c0 = (double)SG[t*153];
    cnt[t] = c0; safe[t] = (c0 > 0.0) ? c0 : 1.0;
  }
  __syncthreads();
  for (int e=t; e<160; e+=256){
    int c = e >> 4, a = e & 15;
    mean[c][a] = (double)SG[c*153 + 1 + a] / safe[c];
  }
  __syncthreads();
  for (int e=t; e<2560; e+=256){
    int c = e >> 8, ab = e & 255, a = ab >> 4, b2 = ab & 15;
    int lo = a < b2 ? a : b2, hi = a < b2 ? b2 : a;
    int ti = lo*(33 - lo)/2 + (hi - lo);
    Sig[c][a][b2] = (double)SG[c*153 + 17 + ti]/safe[c] - mean[c][a]*mean[c][b2] + ((a==b2)?1.0:0.0);
  }
  __syncthreads();
  if (t < 10){
    for (int a=0;a<16;++a)
      for (int b2=0;b2<16;++b2) Inv[t][a][b2] = Sig[t][a][b2];
    double ld2 = 0.0;
    for (int k=0;k<16;++k){
      double v = Inv[t][k][k];
      for (int j=0;j<k;++j) v -= Inv[t][k][j]*Inv[t][k][j];
      v = fmax(v, 1e-280);
      double lkk = sqrt(v);
      Inv[t][k][k] = lkk; ld2 += log(lkk);
      for (int i=k+1;i<16;++i){
        double w = Inv[t][i][k];
        for (int j=0;j<k;++j) w -= Inv[t][i][j]*Inv[t][k][j];
        Inv[t][i][k] = w / lkk;
      }
    }
    ldet[t] = 2.0*ld2;
    for (int j=0;j<16;++j){
      double dj = 1.0 / Inv[t][j][j];
      Inv[t][j][j] = dj;
      for (int i=j+1;i<16;++i){
        double ssum = Inv[t][i][j]*dj;
        for (int k=j+1;k<i;++k) ssum += Inv[t][i][k]*Inv[t][k][j];
        Inv[t][i][j] = -ssum / Inv[t][i][i];
      }
    }
    double dg[16];
    #pragma unroll
    for (int a=0;a<16;++a){
      double s2 = 0.0;
      for (int k=a;k<16;++k){ double x = Inv[t][k][a]; s2 += x*x; }
      dg[a] = s2;
    }
    for (int a=0;a<16;++a)
      for (int b2=a+1;b2<16;++b2){
        double s2 = 0.0;
        for (int k=b2;k<16;++k) s2 += Inv[t][k][a]*Inv[t][k][b2];
        Inv[t][a][b2] = s2;
      }
    for (int a=0;a<16;++a) Inv[t][a][a] = dg[a];
    for (int a=0;a<16;++a)
      for (int b2=a+1;b2<16;++b2) Inv[t][b2][a] = Inv[t][a][b2];
  }
  __syncthreads();
  double contrib = 0.0;
  if (t < 100){
    int i = t/10, j = t%10;
    if (i != j && cnt[i] > 0.0 && cnt[j] > 0.0){
      double tr = 0.0;
      for (int a=0;a<16;++a)
        for (int b2=0;b2<16;++b2) tr += Inv[j][a][b2]*Sig[i][b2][a];
      double dm[16];
      #pragma unroll
      for (int a=0;a<16;++a) dm[a] = mean[j][a] - mean[i][a];
      double mah = 0.0;
      for (int a=0;a<16;++a){
        double rs = 0.0;
        for (int b2=0;b2<16;++b2) rs += Inv[j][a][b2]*dm[b2];
        mah += dm[a]*rs;
      }
      double kl = 0.5*(tr + mah - 16.0 + ldet[j] - ldet[i]);
      contrib = kl * cnt[i]*cnt[j];
    }
  }
  if (t < 128) red[t] = contrib;
  __syncthreads();
  for (int off=64; off>0; off >>= 1){
    if (t < off) red[t] += red[t+off];
    __syncthreads();
  }
  if (t == 0) out[0] = (float)(red[0] / (16384.0*16384.0*16384.0));
}

// ---------------- host ----------------
extern "C" void kernel_launch(void* const* d_in, const int* in_sizes, int n_in,
                              void* d_out, int out_size, void* d_ws, size_t ws_size,
                              hipStream_t stream){
  (void)in_sizes; (void)n_in; (void)out_size; (void)ws_size;
  const float* X  = (const float*)d_in[0];
  const int* lbl  = (const int*)d_in[1];
  char* ws = (char*)d_ws;
  float*  C    = (float*)(ws + OFF_C);
  float*  Mm   = (float*)(ws + OFF_M);
  float*  P    = (float*)(ws + OFF_P);
  float*  Y0   = (float*)(ws + OFF_Y0);
  float*  Y1   = (float*)(ws + OFF_Y1);
  float*  Y2   = (float*)(ws + OFF_Y2);
  float*  Y3   = (float*)(ws + OFF_Y3);
  float*  CQ   = (float*)(ws + OFF_CQ);
  double* S64  = (double*)(ws + OFF_S64);
  float*  LF   = (float*)(ws + OFF_LF);
  double* T64  = (double*)(ws + OFF_T64);
  float*  V16  = (float*)(ws + OFF_V16);
  float*  UT   = (float*)(ws + OFF_UT);
  float*  UTT  = (float*)(ws + OFF_UTT);
  float*  S16  = (float*)(ws + OFF_S16);
  float*  CS   = (float*)(ws + OFF_CS);
  float*  TRC  = (float*)(ws + OFF_TR);
  float*  SCAL = (float*)(ws + OFF_SCAL);
  float*  STAT = (float*)(ws + OFF_STAT);
  float*  F    = (float*)(ws + OFF_F);
  float*  OUT  = (float*)d_out;

  hipMemsetAsync(C, 0, 4*1024*1024, stream);
  hipMemsetAsync(Mm, 0, 4*1024*1024, stream);
  hipMemsetAsync(ws + OFF_CS, 0, 12800, stream);   // CS + TR + SCAL + STAT

  colsum_k<<<64, 256, 0, stream>>>(X, CS);
  syrk_k<<<36*24, 256, 0, stream>>>(X, C);
  formC_k<<<4096, 256, 0, stream>>>(C, CS, TRC);
  scal_k<<<1, 1, 0, stream>>>(TRC, SCAL);
  formChat_k<<<4096, 256, 0, stream>>>(C, SCAL);       // C := Chat (in place)
  syrkM_k<<<36*8, 256, 0, stream>>>(C, Mm);            // Macc = Chat^2 (upper)
  formM_k<<<4096, 256, 0, stream>>>(Mm);               // M = 2*Macc - I, mirrored
  rng_k<<<256, 256, 0, stream>>>(Y0);

  // Chebyshev stage in M: U_{s+1} = 2 M U_s - U_{s-1} (T_10(M) == T_20(Chat))
  auto cheb = [&](float* in, float* z0, float* z1, float* z2) -> float* {
    float* bufs[3] = {z0, z1, z2};
    float* prev = in;
    float* cur = in;
    for (int s=0; s<CHEB_D; ++s){
      float* dst = bufs[s % 3];
      mv_k<<<256, 256, 0, stream>>>(cur, Mm, P);
      combine_k<<<64, 256, 0, stream>>>(P, prev, dst, (s == 0) ? 0 : 1);
      prev = cur; cur = dst;
    }
    return cur;   // = z0 for CHEB_D=10
  };
  auto cholqr = [&](float* Yin, float* Qout){
    gram_k<<<256, 256, 0, stream>>>(Yin, Yin, S64);
    chol_k<<<1, 64, 0, stream>>>(S64, LF);
    applysolve_k<<<4, 256, 0, stream>>>(Yin, LF, Qout);
  };

  // stage 1: filter random block, single CholQR (conditioning only)
  cheb(Y0, Y1, Y2, Y3);                // -> Y1
  cholqr(Y1, Y2);                      // Q1 = Y2
  // stage 2 + CholQR2 (full orthonormality before RR)
  cheb(Y2, Y0, Y1, Y3);                // -> Y0
  cholqr(Y0, Y1);
  cholqr(Y1, Y2);                      // Qf = Y2

  // Rayleigh-Ritz in M-space: T = Q^T M Q
  mv_k<<<256, 256, 0, stream>>>(Y2, Mm, P);
  combine_k<<<64, 256, 0, stream>>>(P, Y2, CQ, 0);     // CQ = Q M
  gram_k<<<256, 256, 0, stream>>>(Y2, CQ, T64);
  eig16_k<<<1, 64, 0, stream>>>(T64, V16);
  buildUt_k<<<64, 256, 0, stream>>>(V16, Y2, UT, UTT);

  // project and GMM loss
  s16_k<<<1, 256, 0, stream>>>(CS, UT, S16);
  proj_k<<<256, 256, 0, stream>>>(X, UTT, S16, F);
  stats_k<<<64, 256, 0, stream>>>(F, lbl, STAT);
  final_k<<<1, 256, 0, stream>>>(STAT, OUT);
}

// Round 7
// 1665.069 us; speedup vs baseline: 1.1486x; 1.1486x over previous
//
#include <hip/hip_runtime.h>
#include <math.h>

// ---------------- problem constants (fixed inputs: key 0) ----------------
#define BN 16384
#define DN 1024
#define CHEB_D 8   // Chebyshev degree per stage IN M (== degree 16 in C)

// ---------------- workspace layout (bytes, all 256-aligned) ----------------
static constexpr size_t OFF_C    = 0x000000;  // f32 [1024*1024]  G -> C -> Chat   [ZERO]
static constexpr size_t OFF_P    = 0x400000;  // f32 [16][64][1024] mv partials
static constexpr size_t OFF_Y0   = 0x800000;  // f32 [64][1024]
static constexpr size_t OFF_Y1   = 0x840000;
static constexpr size_t OFF_Y2   = 0x880000;
static constexpr size_t OFF_Y3   = 0x8C0000;
static constexpr size_t OFF_CQ   = 0x900000;  // f32 [64][1024]
static constexpr size_t OFF_S64  = 0x940000;  // f64 [64*64] gram
static constexpr size_t OFF_LF   = 0x948000;  // f32 [64*64] chol factor (recip diag)
static constexpr size_t OFF_T64  = 0x950000;  // f64 [64*64] RR matrix (in M-space)
static constexpr size_t OFF_V16  = 0x958000;  // f32 [64*16] top-16 eigvecs
static constexpr size_t OFF_UT   = 0x960000;  // f32 [16][1024]
static constexpr size_t OFF_UTT  = 0x970000;  // f32 [1024][16]
static constexpr size_t OFF_S16  = 0x980000;  // f32 [16]
static constexpr size_t OFF_CS   = 0x980100;  // f32 [1024] colsum           [ZERO]
static constexpr size_t OFF_TR   = 0x981100;  // f32 [1] trace               [ZERO]
static constexpr size_t OFF_SCAL = 0x981200;  // f32 [2] mid, inv_e
static constexpr size_t OFF_STAT = 0x981300;  // f32 [10*153] stats          [ZERO]
static constexpr size_t OFF_F    = 0x990000;  // f32 [16384*16] features
static constexpr size_t OFF_M    = 0xA90000;  // f32 [1024*1024] M = 2*Chat^2 - I [ZERO]
// end 0xE90000 (~15.6 MB of ws used)

// ---------------- kernels ----------------

__global__ __launch_bounds__(256) void colsum_k(const float* __restrict__ X, float* __restrict__ cs){
  int b = blockIdx.x, t = threadIdx.x;
  float a0=0.f,a1=0.f,a2=0.f,a3=0.f;
  for (int r=0; r<256; ++r){
    const float4 v = *(const float4*)(X + (size_t)(b*256 + r)*1024 + t*4);
    a0 += v.x; a1 += v.y; a2 += v.z; a3 += v.w;
  }
  atomicAdd(&cs[t*4+0], a0); atomicAdd(&cs[t*4+1], a1);
  atomicAdd(&cs[t*4+2], a2); atomicAdd(&cs[t*4+3], a3);
}

// SYRK body: upper 128x128 tiles of A^T A, conflict-free fragment layout.
template<int KCHUNK>
__device__ __forceinline__ void syrk_body(const float* __restrict__ X, float* __restrict__ G, int KMAX){
  int bx = blockIdx.x;
  int tp = bx % 36, ks = bx / 36;
  int ti = 0, rem = tp;
  while (rem >= 8 - ti){ rem -= 8 - ti; ++ti; }
  int tj = ti + rem;                      // ti <= tj
  int k0 = ks * KCHUNK;
  int kend = k0 + KCHUNK; if (kend > KMAX) kend = KMAX;
  __shared__ __attribute__((aligned(16))) float Xa[16][132];
  __shared__ __attribute__((aligned(16))) float Xb[16][132];
  int t = threadIdx.x;
  int tx = t & 15, ty = t >> 4;
  int kk0 = t >> 5, f4 = t & 31;
  const float* ba = X + (size_t)kk0*1024 + ti*128 + f4*4;
  const float* bb = X + (size_t)kk0*1024 + tj*128 + f4*4;
  float4 pa0, pa1, pb0, pb1;
  {
    size_t o = (size_t)k0*1024;
    pa0 = *(const float4*)(ba + o);
    pb0 = *(const float4*)(bb + o);
    pa1 = *(const float4*)(ba + o + 8*1024);
    pb1 = *(const float4*)(bb + o + 8*1024);
  }
  float acc[8][8];
  #pragma unroll
  for (int i=0;i<8;++i)
    #pragma unroll
    for (int j=0;j<8;++j) acc[i][j] = 0.f;
  for (int kc = k0; kc < kend; kc += 16){
    __syncthreads();
    *(float4*)&Xa[kk0][f4*4]   = pa0;
    *(float4*)&Xa[kk0+8][f4*4] = pa1;
    *(float4*)&Xb[kk0][f4*4]   = pb0;
    *(float4*)&Xb[kk0+8][f4*4] = pb1;
    __syncthreads();
    if (kc + 16 < kend){
      size_t o = (size_t)(kc+16)*1024;
      pa0 = *(const float4*)(ba + o);
      pb0 = *(const float4*)(bb + o);
      pa1 = *(const float4*)(ba + o + 8*1024);
      pb1 = *(const float4*)(bb + o + 8*1024);
    }
    #pragma unroll
    for (int kk=0; kk<16; ++kk){
      float a[8], b[8];
      *(float4*)&a[0] = *(const float4*)&Xa[kk][tx*4];
      *(float4*)&a[4] = *(const float4*)&Xa[kk][64 + tx*4];
      *(float4*)&b[0] = *(const float4*)&Xb[kk][ty*4];
      *(float4*)&b[4] = *(const float4*)&Xb[kk][64 + ty*4];
      #pragma unroll
      for (int i=0;i<8;++i)
        #pragma unroll
        for (int j=0;j<8;++j) acc[i][j] += a[i]*b[j];
    }
  }
  #pragma unroll
  for (int i=0;i<8;++i){
    int ri = ti*128 + ((i<4) ? (tx*4+i) : (64 + tx*4 + (i-4)));
    #pragma unroll
    for (int j=0;j<8;++j){
      int cj = tj*128 + ((j<4) ? (ty*4+j) : (64 + ty*4 + (j-4)));
      atomicAdd(&G[(size_t)ri*1024 + cj], acc[i][j]);
    }
  }
}

__global__ __launch_bounds__(256, 3) void syrk_k(const float* __restrict__ X, float* __restrict__ G){
  syrk_body<688>(X, G, 16384);
}
__global__ __launch_bounds__(256, 3) void syrkM_k(const float* __restrict__ X, float* __restrict__ G){
  syrk_body<128>(X, G, 1024);
}

__global__ __launch_bounds__(256) void formC_k(float* __restrict__ C, const float* __restrict__ cs, float* __restrict__ tr){
  int g = blockIdx.x*256 + threadIdx.x;
  int i = g >> 10, j = g & 1023;
  if (j < i) return;
  float v = C[g] - cs[i]*cs[j]*(1.0f/16384.0f);
  C[g] = v;
  C[j*1024 + i] = v;
  if (i == j) atomicAdd(tr, v);
}

__global__ void scal_k(const float* __restrict__ tr, float* __restrict__ scal){
  float trD = tr[0] * (1.0f/1024.0f);
  float c = 1.40f * trD, a = 0.25f * trD;
  scal[0] = 0.5f*(c + a);       // mid
  scal[1] = 2.0f/(c - a);       // 1/e
}

__global__ __launch_bounds__(256) void formChat_k(float* __restrict__ C, const float* __restrict__ scal){
  int g = blockIdx.x*256 + threadIdx.x;
  int i = g >> 10, j = g & 1023;
  float mid = scal[0], ie = scal[1];
  C[g] = ie*(C[g] - ((i==j) ? mid : 0.f));
}

__global__ __launch_bounds__(256) void formM_k(float* __restrict__ M){
  int g = blockIdx.x*256 + threadIdx.x;
  int i = g >> 10, j = g & 1023;
  if (j < i) return;
  float v = 2.f*M[g] - ((i==j) ? 1.f : 0.f);
  M[g] = v;
  M[j*1024 + i] = v;
}

__global__ void rng_k(float* __restrict__ Y){
  int idx = blockIdx.x*256 + threadIdx.x;   // 65536
  unsigned h = (unsigned)idx * 2654435761u;
  h ^= h >> 16; h *= 2246822519u; h ^= h >> 13; h *= 3266489917u; h ^= h >> 16;
  Y[idx] = (float)(h & 0xFFFFFFu) * (2.0f/16777216.0f) - 1.0f;
}

__global__ __launch_bounds__(256) void mv_k(const float* __restrict__ Yt, const float* __restrict__ Cm, float* __restrict__ P){
  int bx = blockIdx.x;
  int nt = bx & 15, ks = bx >> 4;
  int n0 = nt*64, k0 = ks*64;
  __shared__ __attribute__((aligned(16))) float At[64][68];
  __shared__ __attribute__((aligned(16))) float Bt[64][68];
  int t = threadIdx.x;
  #pragma unroll
  for (int w=0; w<4; ++w){
    int job = t + 256*w;
    int m  = job >> 4, f4 = job & 15;
    float4 v = *(const float4*)(Yt + (size_t)m*1024 + k0 + f4*4);
    At[f4*4+0][m] = v.x; At[f4*4+1][m] = v.y; At[f4*4+2][m] = v.z; At[f4*4+3][m] = v.w;
    int kk = job >> 4, fn = job & 15;
    *(float4*)&Bt[kk][fn*4] = *(const float4*)(Cm + (size_t)(k0+kk)*1024 + n0 + fn*4);
  }
  __syncthreads();
  int tm = t & 15, tn = t >> 4;
  float acc[4][4];
  #pragma unroll
  for (int i=0;i<4;++i)
    #pragma unroll
    for (int j=0;j<4;++j) acc[i][j]=0.f;
  for (int kk=0; kk<64; ++kk){
    float4 a = *(const float4*)&At[kk][tm*4];
    float4 b = *(const float4*)&Bt[kk][tn*4];
    float av[4] = {a.x,a.y,a.z,a.w};
    float bv[4] = {b.x,b.y,b.z,b.w};
    #pragma unroll
    for (int i=0;i<4;++i)
      #pragma unroll
      for (int j=0;j<4;++j) acc[i][j] += av[i]*bv[j];
  }
  #pragma unroll
  for (int i=0;i<4;++i){
    float4 o; o.x=acc[i][0]; o.y=acc[i][1]; o.z=acc[i][2]; o.w=acc[i][3];
    *(float4*)(P + (size_t)(ks*64 + tm*4 + i)*1024 + n0 + tn*4) = o;
  }
}

__global__ __launch_bounds__(256) void combine_k(const float* __restrict__ P, const float* __restrict__ Tk1,
                                                 float* __restrict__ out, int mode){
  int idx = (blockIdx.x*256 + threadIdx.x)*4;
  float s0=0.f,s1=0.f,s2=0.f,s3=0.f;
  #pragma unroll
  for (int ks=0; ks<16; ++ks){
    const float4 p = *(const float4*)(P + (size_t)ks*65536 + idx);
    s0 += p.x; s1 += p.y; s2 += p.z; s3 += p.w;
  }
  float4 o;
  if (mode == 0){
    o.x=s0; o.y=s1; o.z=s2; o.w=s3;
  } else {
    const float4 t1 = *(const float4*)(Tk1 + idx);
    o.x = 2.f*s0 - t1.x; o.y = 2.f*s1 - t1.y;
    o.z = 2.f*s2 - t1.z; o.w = 2.f*s3 - t1.w;
  }
  *(float4*)(out+idx) = o;
}

__global__ __launch_bounds__(256) void gram_k(const float* __restrict__ A, const float* __restrict__ Bm, double* __restrict__ S){
  int bx = blockIdx.x;
  int i = bx >> 2, jg = bx & 3;
  __shared__ __attribute__((aligned(16))) float Ai[1024];
  __shared__ double red[16][17];
  int t = threadIdx.x;
  ((float4*)Ai)[t] = ((const float4*)(A + (size_t)i*1024))[t];
  __syncthreads();
  int jl = t >> 4, kp = t & 15;
  const float* Br = Bm + (size_t)(jg*16 + jl)*1024 + kp*64;
  const float* Ar = Ai + kp*64;
  double acc = 0.0;
  #pragma unroll 8
  for (int kk=0; kk<64; ++kk) acc += (double)Br[kk] * (double)Ar[kk];
  red[jl][kp] = acc;
  __syncthreads();
  if (t < 16){
    double s = 0.0;
    #pragma unroll
    for (int p2=0; p2<16; ++p2) s += red[t][p2];
    S[i*64 + jg*16 + t] = s;
  }
}

// fp64 Cholesky of 64x64, single wave, fixed-trip masked rank-1 updates.
__global__ __launch_bounds__(64) void chol_k(const double* __restrict__ S, float* __restrict__ Lf){
  __shared__ double L[64][65];
  __shared__ double col[64];
  int t = threadIdx.x;
  for (int e=t; e<4096; e+=64) L[e>>6][e&63] = S[e];
  __syncthreads();
  for (int k=0; k<64; ++k){
    double lkk = sqrt(fmax(L[k][k], 1e-280));
    double r = 1.0/lkk;
    double ck = (t > k) ? L[t][k]*r : 0.0;
    col[t] = ck;
    if (t == k) L[k][k] = lkk;
    if (t > k)  L[t][k] = ck;
    __syncthreads();
    #pragma unroll
    for (int j=0; j<64; j+=8){
      L[t][j+0] -= ck*col[j+0];
      L[t][j+1] -= ck*col[j+1];
      L[t][j+2] -= ck*col[j+2];
      L[t][j+3] -= ck*col[j+3];
      L[t][j+4] -= ck*col[j+4];
      L[t][j+5] -= ck*col[j+5];
      L[t][j+6] -= ck*col[j+6];
      L[t][j+7] -= ck*col[j+7];
    }
    __syncthreads();
  }
  for (int e=t; e<4096; e+=64){
    int i = e >> 6, j = e & 63;
    Lf[e] = (j < i) ? (float)L[i][j] : ((j == i) ? (float)(1.0/L[i][i]) : 0.f);
  }
}

__global__ __launch_bounds__(256) void applysolve_k(const float* __restrict__ Yin, const float* __restrict__ Lf, float* __restrict__ Qout){
  int k = blockIdx.x*256 + threadIdx.x;
  float z[64];
  #pragma unroll
  for (int c=0; c<64; ++c){
    float v = Yin[(size_t)c*1024 + k];
    #pragma unroll
    for (int j=0; j<c; ++j) v -= Lf[c*64+j]*z[j];
    z[c] = v * Lf[c*64+c];   // diag stores reciprocal
  }
  #pragma unroll
  for (int c=0; c<64; ++c) Qout[(size_t)c*1024 + k] = z[c];
}

// ---------- 256-thread fp32 64x64 symmetric top-16 eigensolver ----------
__device__ __forceinline__ float wsumf(float v){
  #pragma unroll
  for (int off=32; off; off>>=1) v += __shfl_xor(v, off, 64);
  return v;
}
__device__ __forceinline__ float wminf(float v){
  #pragma unroll
  for (int off=32; off; off>>=1) v = fminf(v, __shfl_xor(v, off, 64));
  return v;
}
__device__ __forceinline__ float wmaxf(float v){
  #pragma unroll
  for (int off=32; off; off>>=1) v = fmaxf(v, __shfl_xor(v, off, 64));
  return v;
}

__global__ __launch_bounds__(256) void eig16_k(const double* __restrict__ Tin, float* __restrict__ V16){
  __shared__ float A[64][65];          // matrix; reflectors stored in lower columns
  __shared__ float vS[64], qS[64];
  __shared__ float pp[4][64];
  __shared__ float dF[64], eF[64], e2F[64], kapS[64];
  __shared__ float lamF[16];
  __shared__ float IV[5][64][16];
  __shared__ float W[16][68];
  int t = threadIdx.x;
  int r = t & 63, p4 = t >> 6;          // row, column-slice

  for (int e=t; e<4096; e+=256){
    int i = e >> 6, j = e & 63;
    A[i][j] = (float)(0.5*(Tin[i*64+j] + Tin[(size_t)j*64+i]));
  }
  __syncthreads();

  // ---- Householder tridiagonalization: thread (r,p4) owns A[r][p4*16 .. +16) ----
  for (int k=0; k<62; ++k){
    float ck = (r > k) ? A[r][k] : 0.f;   // all waves read (pre-write)
    float x1 = A[k+1][k];
    float sig = wsumf(ck*ck);             // per-wave redundant reduce (identical)
    float rr = sqrtf(sig);
    float alpha = (x1 >= 0.f) ? -rr : rr;
    float kappa = sig - alpha*x1;
    float kinv = (kappa > 1e-30f) ? 1.f/kappa : 0.f;
    float v = ck;
    if (r == k+1) v = x1 - alpha;
    if (kinv == 0.f) v = 0.f;
    if (p4 == 0){
      vS[r] = v;
      if (r == 0){ eF[k] = (kinv==0.f) ? 0.f : alpha; kapS[k] = (kinv==0.f) ? 0.f : kappa; }
    }
    __syncthreads();
    if (p4 == 0 && r > k) A[r][k] = v;    // reflector store; races benign (vS[k]=0 kills its use)
    float prt = 0.f;
    int j0 = p4*16;
    #pragma unroll
    for (int jj=0; jj<16; ++jj) prt += A[r][j0+jj]*vS[j0+jj];
    pp[p4][r] = prt;
    __syncthreads();
    float pfull = pp[0][r] + pp[1][r] + pp[2][r] + pp[3][r];
    float pi = (r > k) ? pfull*kinv : 0.f;
    float vp = wsumf(v*pi);
    float Kc = vp*0.5f*kinv;
    float q = (r > k) ? (pi - Kc*v) : 0.f;
    if (p4 == 0) qS[r] = q;
    __syncthreads();
    #pragma unroll
    for (int jj=0; jj<16; ++jj){
      int j = j0 + jj;
      A[r][j] -= v*qS[j] + q*vS[j];       // no-op for j<=k (vS,qS zero there)
    }
    __syncthreads();
  }

  // ---- extract tridiagonal ----
  if (t < 64) dF[t] = A[t][t];
  if (t == 0){ eF[62] = A[63][62]; eF[63] = 0.f; kapS[62] = 0.f; kapS[63] = 0.f; }
  __syncthreads();
  if (t < 64) e2F[t] = eF[t]*eF[t];
  __syncthreads();

  // ---- Gershgorin bounds (redundant per wave) ----
  float em1 = (r > 0) ? fabsf(eF[r-1]) : 0.f;
  float ep  = fabsf(eF[r]);
  float glo = wminf(dF[r] - em1 - ep);
  float ghi = wmaxf(dF[r] + em1 + ep);
  float span = ghi - glo + 1.f;
  float lo = glo - 0.001f*span, hi = ghi + 0.001f*span;

  // ---- Sturm bisection (redundant across waves): eigen index 48 + (t&15) ----
  int m = 48 + (t & 15);
  const float PIV = 1e-10f;
  for (int it=0; it<26; ++it){
    float x = 0.5f*(lo + hi);
    float qq = dF[0] - x;
    int c = (qq < 0.f) ? 1 : 0;
    #pragma unroll 1
    for (int j=1; j<64; ++j){
      float qs = (fabsf(qq) < PIV) ? ((qq < 0.f) ? -PIV : PIV) : qq;
      qq = dF[j] - x - e2F[j-1]/qs;
      c += (qq < 0.f) ? 1 : 0;
    }
    if (c <= m) lo = x; else hi = x;
  }
  if (t < 16) lamF[t] = 0.5f*(lo + hi);
  __syncthreads();

  // ---- inverse iteration (lanes 0..15), tridiagonal LU in LDS ----
  #define DLa(i) IV[0][i][t]
  #define DDa(i) IV[1][i][t]
  #define DUa(i) IV[2][i][t]
  #define DU2a(i) IV[3][i][t]
  #define Bv(i)  IV[4][i][t]
  if (t < 16){
    float lam = lamF[t];
    const float PIVF = 1e-6f;
    for (int i=0; i<64; ++i){
      DDa(i) = dF[i] - lam;
      DU2a(i) = 0.f;
      if (i < 63){ DUa(i) = eF[i]; DLa(i) = eF[i]; }
      unsigned hsh = (unsigned)(i*131 + t*1009 + 7);
      hsh ^= hsh >> 13; hsh *= 2654435761u; hsh ^= hsh >> 16;
      Bv(i) = (float)(hsh & 0xFFFF) * (1.5f/65536.0f) + 0.25f;
    }
    unsigned long long piv = 0ull;
    for (int i=0; i<63; ++i){
      float di = DDa(i), dli = DLa(i);
      if (fabsf(di) >= fabsf(dli)){
        if (fabsf(di) < PIVF) di = (di < 0.f) ? -PIVF : PIVF;
        float f = dli/di;
        DDa(i) = di; DLa(i) = f;
        DDa(i+1) -= f*DUa(i);
      } else {
        float f = di/dli;
        DDa(i) = dli; DLa(i) = f;
        float tmp = DUa(i);
        DUa(i) = DDa(i+1);
        DDa(i+1) = tmp - f*DDa(i+1);
        if (i < 62){ DU2a(i) = DUa(i+1); DUa(i+1) = -f*DUa(i+1); }
        piv |= (1ull << i);
      }
    }
    #pragma unroll 1
    for (int iter=0; iter<2; ++iter){
      for (int i=0; i<63; ++i){
        if (!((piv >> i) & 1ull)){
          Bv(i+1) -= DLa(i)*Bv(i);
        } else {
          float tm = Bv(i);
          Bv(i) = Bv(i+1);
          Bv(i+1) = tm - DLa(i)*Bv(i);
        }
      }
      float p63 = DDa(63); if (fabsf(p63) < PIVF) p63 = (p63 < 0.f) ? -PIVF : PIVF;
      Bv(63) = Bv(63)/p63;
      float p62 = DDa(62); if (fabsf(p62) < PIVF) p62 = (p62 < 0.f) ? -PIVF : PIVF;
      Bv(62) = (Bv(62) - DUa(62)*Bv(63))/p62;
      for (int i=61; i>=0; --i){
        float pi2 = DDa(i); if (fabsf(pi2) < PIVF) pi2 = (pi2 < 0.f) ? -PIVF : PIVF;
        Bv(i) = (Bv(i) - DUa(i)*Bv(i+1) - DU2a(i)*Bv(i+2))/pi2;
      }
      float ss = 0.f;
      for (int i=0; i<64; ++i){ float z = Bv(i); ss += z*z; }
      float rn = rsqrtf(fmaxf(ss, 1e-30f));
      for (int i=0; i<64; ++i) Bv(i) *= rn;
    }
    for (int i=0; i<64; ++i) W[t][i] = Bv(i);
  }
  __syncthreads();
  #undef DLa
  #undef DDa
  #undef DUa
  #undef DU2a
  #undef Bv

  // ---- MGS re-orth: wave 0 computes/writes, all threads hit barriers ----
  for (int c=0; c<16; ++c){
    float wi = (t < 64) ? W[c][t] : 0.f;
    float s2 = wsumf(wi*wi);
    float rn = rsqrtf(fmaxf(s2, 1e-30f));
    wi *= rn;
    if (t < 64) W[c][t] = wi;
    __syncthreads();
    for (int c2=c+1; c2<16; ++c2){
      float w2 = (t < 64) ? W[c2][t] : 0.f;
      float d2 = wsumf(wi*w2);
      if (t < 64) W[c2][t] -= d2*wi;
    }
    __syncthreads();
  }

  // ---- back-transform: 4 vecs/wave, 16 lanes/vec, no barriers needed ----
  int cL = (p4 << 2) + (r >> 4);        // eigvec index 0..15
  int part = r & 15;                    // 16 parts x 4 elements
  for (int k=61; k>=0; --k){
    float kpd = kapS[k];
    if (kpd == 0.f) continue;           // wave-uniform
    float invk = 1.f/kpd;
    float vv[4];
    float ps = 0.f;
    #pragma unroll
    for (int mm=0; mm<4; ++mm){
      int i = part*4 + mm;
      vv[mm] = (i > k) ? A[i][k] : 0.f;
      ps += vv[mm]*W[cL][i];
    }
    ps += __shfl_xor(ps, 1, 64);
    ps += __shfl_xor(ps, 2, 64);
    ps += __shfl_xor(ps, 4, 64);
    ps += __shfl_xor(ps, 8, 64);
    float sc = ps * invk;
    #pragma unroll
    for (int mm=0; mm<4; ++mm){
      int i = part*4 + mm;
      W[cL][i] -= vv[mm]*sc;
    }
  }
  __syncthreads();

  for (int e=t; e<1024; e+=256){
    int j = e >> 4, c = e & 15;
    V16[e] = W[c][j];
  }
}

__global__ __launch_bounds__(256) void buildUt_k(const float* __restrict__ V16,
                                                 const float* __restrict__ Qt, float* __restrict__ Ut, float* __restrict__ UtT){
  int bx = blockIdx.x;
  int c = bx & 15, kc = bx >> 4;
  int k = kc*256 + threadIdx.x;
  float acc = 0.f;
  #pragma unroll
  for (int j=0; j<64; ++j) acc += V16[j*16 + c] * Qt[(size_t)j*1024 + k];
  Ut[(size_t)c*1024 + k] = acc;
  UtT[(size_t)k*16 + c] = acc;
}

__global__ void s16_k(const float* __restrict__ cs, const float* __restrict__ Ut, float* __restrict__ s16){
  __shared__ float red[16][17];
  int t = threadIdx.x;
  int c = t & 15, part = t >> 4;
  float acc = 0.f;
  for (int d=0; d<64; ++d) acc += cs[part*64 + d] * Ut[(size_t)c*1024 + part*64 + d];
  red[c][part] = acc;
  __syncthreads();
  if (t < 16){
    float s = 0.f;
    #pragma unroll
    for (int p2=0; p2<16; ++p2) s += red[t][p2];
    s16[t] = s * (1.0f/16384.0f);
  }
}

__global__ __launch_bounds__(256) void proj_k(const float* __restrict__ X, const float* __restrict__ UtT,
                                              const float* __restrict__ s16, float* __restrict__ F){
  int r0 = blockIdx.x * 64;
  int t = threadIdx.x;
  __shared__ __attribute__((aligned(16))) float uts[16384];   // [1024][16]
  #pragma unroll
  for (int w=0; w<16; ++w)
    ((float4*)uts)[t + 256*w] = ((const float4*)UtT)[t + 256*w];
  __syncthreads();
  int row = t & 63, kp = t >> 6;
  const float* xr = X + (size_t)(r0 + row)*1024 + kp*256;
  const float* ut = uts + kp*256*16;
  float acc[16];
  #pragma unroll
  for (int c=0;c<16;++c) acc[c] = 0.f;
  for (int dd=0; dd<256; dd+=4){
    float4 xv4 = *(const float4*)(xr + dd);
    float xv[4] = {xv4.x, xv4.y, xv4.z, xv4.w};
    #pragma unroll
    for (int u=0; u<4; ++u)
      #pragma unroll
      for (int c=0;c<16;++c) acc[c] += xv[u] * ut[(dd+u)*16 + c];
  }
  __shared__ float part[4][64][16];
  #pragma unroll
  for (int c=0;c<16;++c) part[kp][row][c] = acc[c];
  __syncthreads();
  int cq = t >> 6;
  #pragma unroll
  for (int ccx=0; ccx<4; ++ccx){
    int c = cq*4 + ccx;
    float v = part[0][row][c] + part[1][row][c] + part[2][row][c] + part[3][row][c] - s16[c];
    F[(size_t)(r0 + row)*16 + c] = v;
  }
}

__global__ __launch_bounds__(256) void stats_k(const float* __restrict__ F, const int* __restrict__ lbl, float* __restrict__ SG){
  __shared__ float st[10][154];
  int t = threadIdx.x;
  for (int e=t; e<1540; e+=256) st[e/154][e%154] = 0.f;
  __syncthreads();
  int r = blockIdx.x*256 + t;
  float f[16];
  #pragma unroll
  for (int w=0; w<4; ++w){
    float4 v = *(const float4*)(F + (size_t)r*16 + w*4);
    f[w*4+0]=v.x; f[w*4+1]=v.y; f[w*4+2]=v.z; f[w*4+3]=v.w;
  }
  int c = lbl[r];
  if ((unsigned)c < 10u){
    float* bs = &st[c][0];
    atomicAdd(&bs[0], 1.f);
    #pragma unroll
    for (int a=0;a<16;++a) atomicAdd(&bs[1+a], f[a]);
    int sidx = 17;
    #pragma unroll
    for (int a=0;a<16;++a)
      #pragma unroll
      for (int b2=a;b2<16;++b2) atomicAdd(&bs[sidx++], f[a]*f[b2]);
  }
  __syncthreads();
  for (int e=t; e<1530; e+=256) atomicAdd(&SG[e], st[e/153][e%153]);
}

__global__ __launch_bounds__(256) void final_k(const float* __restrict__ SG, float* __restrict__ out){
  __shared__ double cnt[10], safe[10], ldet[10];
  __shared__ double mean[10][16];
  __shared__ double Sig[10][16][16];
  __shared__ double Inv[10][16][16];
  __shared__ double red[128];
  int t = threadIdx.x;
  if (t < 10){
    double c0 = (double)SG[t*153];
    cnt[t] = c0; safe[t] = (c0 > 0.0) ? c0 : 1.0;
  }
  __syncthreads();
  for (int e=t; e<160; e+=256){
    int c = e >> 4, a = e & 15;
    mean[c][a] = (double)SG[c*153 + 1 + a] / safe[c];
  }
  __syncthreads();
  for (int e=t; e<2560; e+=256){
    int c = e >> 8, ab = e & 255, a = ab >> 4, b2 = ab & 15;
    int lo = a < b2 ? a : b2, hi = a < b2 ? b2 : a;
    int ti = lo*(33 - lo)/2 + (hi - lo);
    Sig[c][a][b2] = (double)SG[c*153 + 17 + ti]/safe[c] - mean[c][a]*mean[c][b2] + ((a==b2)?1.0:0.0);
  }
  __syncthreads();
  if (t < 10){
    for (int a=0;a<16;++a)
      for (int b2=0;b2<16;++b2) Inv[t][a][b2] = Sig[t][a][b2];
    double ld2 = 0.0;
    for (int k=0;k<16;++k){
      double v = Inv[t][k][k];
      for (int j=0;j<k;++j) v -= Inv[t][k][j]*Inv[t][k][j];
      v = fmax(v, 1e-280);
      double lkk = sqrt(v);
      Inv[t][k][k] = lkk; ld2 += log(lkk);
      for (int i=k+1;i<16;++i){
        double w = Inv[t][i][k];
        for (int j=0;j<k;++j) w -= Inv[t][i][j]*Inv[t][k][j];
        Inv[t][i][k] = w / lkk;
      }
    }
    ldet[t] = 2.0*ld2;
    for (int j=0;j<16;++j){
      double dj = 1.0 / Inv[t][j][j];
      Inv[t][j][j] = dj;
      for (int i=j+1;i<16;++i){
        double ssum = Inv[t][i][j]*dj;
        for (int k=j+1;k<i;++k) ssum += Inv[t][i][k]*Inv[t][k][j];
        Inv[t][i][j] = -ssum / Inv[t][i][i];
      }
    }
    double dg[16];
    #pragma unroll
    for (int a=0;a<16;++a){
      double s2 = 0.0;
      for (int k=a;k<16;++k){ double x = Inv[t][k][a]; s2 += x*x; }
      dg[a] = s2;
    }
    for (int a=0;a<16;++a)
      for (int b2=a+1;b2<16;++b2){
        double s2 = 0.0;
        for (int k=b2;k<16;++k) s2 += Inv[t][k][a]*Inv[t][k][b2];
        Inv[t][a][b2] = s2;
      }
    for (int a=0;a<16;++a) Inv[t][a][a] = dg[a];
    for (int a=0;a<16;++a)
      for (int b2=a+1;b2<16;++b2) Inv[t][b2][a] = Inv[t][a][b2];
  }
  __syncthreads();
  double contrib = 0.0;
  if (t < 100){
    int i = t/10, j = t%10;
    if (i != j && cnt[i] > 0.0 && cnt[j] > 0.0){
      double tr = 0.0;
      for (int a=0;a<16;++a)
        for (int b2=0;b2<16;++b2) tr += Inv[j][a][b2]*Sig[i][b2][a];
      double dm[16];
      #pragma unroll
      for (int a=0;a<16;++a) dm[a] = mean[j][a] - mean[i][a];
      double mah = 0.0;
      for (int a=0;a<16;++a){
        double rs = 0.0;
        for (int b2=0;b2<16;++b2) rs += Inv[j][a][b2]*dm[b2];
        mah += dm[a]*rs;
      }
      double kl = 0.5*(tr + mah - 16.0 + ldet[j] - ldet[i]);
      contrib = kl * cnt[i]*cnt[j];
    }
  }
  if (t < 128) red[t] = contrib;
  __syncthreads();
  for (int off=64; off>0; off >>= 1){
    if (t < off) red[t] += red[t+off];
    __syncthreads();
  }
  if (t == 0) out[0] = (float)(red[0] / (16384.0*16384.0*16384.0));
}

// ---------------- host ----------------
extern "C" void kernel_launch(void* const* d_in, const int* in_sizes, int n_in,
                              void* d_out, int out_size, void* d_ws, size_t ws_size,
                              hipStream_t stream){
  (void)in_sizes; (void)n_in; (void)out_size; (void)ws_size;
  const float* X  = (const float*)d_in[0];
  const int* lbl  = (const int*)d_in[1];
  char* ws = (char*)d_ws;
  float*  C    = (float*)(ws + OFF_C);
  float*  Mm   = (float*)(ws + OFF_M);
  float*  P    = (float*)(ws + OFF_P);
  float*  Y0   = (float*)(ws + OFF_Y0);
  float*  Y1   = (float*)(ws + OFF_Y1);
  float*  Y2   = (float*)(ws + OFF_Y2);
  float*  Y3   = (float*)(ws + OFF_Y3);
  float*  CQ   = (float*)(ws + OFF_CQ);
  double* S64  = (double*)(ws + OFF_S64);
  float*  LF   = (float*)(ws + OFF_LF);
  double* T64  = (double*)(ws + OFF_T64);
  float*  V16  = (float*)(ws + OFF_V16);
  float*  UT   = (float*)(ws + OFF_UT);
  float*  UTT  = (float*)(ws + OFF_UTT);
  float*  S16  = (float*)(ws + OFF_S16);
  float*  CS   = (float*)(ws + OFF_CS);
  float*  TRC  = (float*)(ws + OFF_TR);
  float*  SCAL = (float*)(ws + OFF_SCAL);
  float*  STAT = (float*)(ws + OFF_STAT);
  float*  F    = (float*)(ws + OFF_F);
  float*  OUT  = (float*)d_out;

  hipMemsetAsync(C, 0, 4*1024*1024, stream);
  hipMemsetAsync(Mm, 0, 4*1024*1024, stream);
  hipMemsetAsync(ws + OFF_CS, 0, 12800, stream);   // CS + TR + SCAL + STAT

  colsum_k<<<64, 256, 0, stream>>>(X, CS);
  syrk_k<<<36*24, 256, 0, stream>>>(X, C);
  formC_k<<<4096, 256, 0, stream>>>(C, CS, TRC);
  scal_k<<<1, 1, 0, stream>>>(TRC, SCAL);
  formChat_k<<<4096, 256, 0, stream>>>(C, SCAL);       // C := Chat (in place)
  syrkM_k<<<36*8, 256, 0, stream>>>(C, Mm);            // Macc = Chat^2 (upper)
  formM_k<<<4096, 256, 0, stream>>>(Mm);               // M = 2*Macc - I, mirrored
  rng_k<<<256, 256, 0, stream>>>(Y0);

  // Chebyshev stage in M: U_{s+1} = 2 M U_s - U_{s-1} (T_8(M) == T_16(Chat))
  auto cheb = [&](float* in, float* z0, float* z1, float* z2) -> float* {
    float* bufs[3] = {z0, z1, z2};
    float* prev = in;
    float* cur = in;
    for (int s=0; s<CHEB_D; ++s){
      float* dst = bufs[s % 3];
      mv_k<<<256, 256, 0, stream>>>(cur, Mm, P);
      combine_k<<<64, 256, 0, stream>>>(P, prev, dst, (s == 0) ? 0 : 1);
      prev = cur; cur = dst;
    }
    return cur;
  };
  auto cholqr = [&](float* Yin, float* Qout){
    gram_k<<<256, 256, 0, stream>>>(Yin, Yin, S64);
    chol_k<<<1, 64, 0, stream>>>(S64, LF);
    applysolve_k<<<4, 256, 0, stream>>>(Yin, LF, Qout);
  };

  // stage 1: filter random block, single CholQR (conditioning only)
  float* f1 = cheb(Y0, Y1, Y2, Y3);    // D=8 -> Y2
  cholqr(f1, Y0);                      // Q1 = Y0
  // stage 2 + CholQR2 (full orthonormality before RR)
  float* f2 = cheb(Y0, Y1, Y2, Y3);    // -> Y2
  cholqr(f2, Y1);
  cholqr(Y1, Y3);                      // Qf = Y3

  // Rayleigh-Ritz in M-space: T = Q^T M Q
  mv_k<<<256, 256, 0, stream>>>(Y3, Mm, P);
  combine_k<<<64, 256, 0, stream>>>(P, Y3, CQ, 0);     // CQ = Q M
  gram_k<<<256, 256, 0, stream>>>(Y3, CQ, T64);
  eig16_k<<<1, 256, 0, stream>>>(T64, V16);
  buildUt_k<<<64, 256, 0, stream>>>(V16, Y3, UT, UTT);

  // project and GMM loss
  s16_k<<<1, 256, 0, stream>>>(CS, UT, S16);
  proj_k<<<256, 256, 0, stream>>>(X, UTT, S16, F);
  stats_k<<<64, 256, 0, stream>>>(F, lbl, STAT);
  final_k<<<1, 256, 0, stream>>>(STAT, OUT);
}